// Round 3
// baseline (453.951 us; speedup 1.0000x reference)
//
#include <hip/hip_runtime.h>

// BoltzmannRouter: weights = renorm(top44(softmax(x @ gate_w^T / e)))
// x: (4,4096,2048) f32 ; gate_w: (64,2048) f32 ; out: (4,4096,64) f32
//
// Dataflow: lane = expert (E=64 = wave width). Each wave owns TPW=8 tokens.
//   acc[t] += x[t][k] (SGPR, scalar s_load via AS4) * w[lane][k] (VGPR from LDS)
// -> x never touches LDS/VALU-load path; w LDS reads are 2 b128 per 128
//    FMA-cycles (under the ~1 b128/12cyc/CU LDS port budget) -> FMA-bound.
// Epilogue fully in-wave (lane=expert): bitonic top-44 threshold + softmax.
// Accuracy: f32 main path (2x 1024-add chains, err ~3e-6); if the f32 gap
// between 20th/21st-smallest scores < GAP_EPS, recompute that token in f64
// and re-rank (expected ~0.7% of tokens -> negligible tail).

#define NTOK   16384
#define DIM    2048
#define NEXP   64
#define NACT   44
#define TPW    8
#define NWAVE  4
#define BM     (TPW * NWAVE)   // 32 tokens/block
#define BK     128             // staged w K-tile
#define NSTEP  (DIM / BK)      // 16
#define NCHUNK (BK / 8)        // 16 chunks of KC=8
#define GAP_EPS 2e-4f

typedef float f4 __attribute__((ext_vector_type(4)));
typedef const __attribute__((address_space(4))) f4* cf4p;  // scalar-load path

__device__ __forceinline__ void gload16(const float* g, float* l) {
  __builtin_amdgcn_global_load_lds(
      (const __attribute__((address_space(1))) void*)g,
      (__attribute__((address_space(3))) void*)l, 16, 0, 0);
}

__device__ __forceinline__ float wave_max(float v) {
  #pragma unroll
  for (int j = 32; j > 0; j >>= 1) v = fmaxf(v, __shfl_xor(v, j, 64));
  return v;
}
__device__ __forceinline__ float wave_sum(float v) {
  #pragma unroll
  for (int j = 32; j > 0; j >>= 1) v += __shfl_xor(v, j, 64);
  return v;
}

__global__ __launch_bounds__(256) void boltzmann_router_kernel(
    const float* __restrict__ x, const float* __restrict__ gw,
    float* __restrict__ out) {
  __shared__ float wlds[2][NEXP * BK];  // 2 x 32 KB

  const int t  = threadIdx.x;
  const int ln = t & 63;
  const int wv = __builtin_amdgcn_readfirstlane(t >> 6);  // SGPR wave id
  const int tokw = blockIdx.x * BM + wv * TPW;

  const int lrow = ln >> 5;   // 0..1: row within 2-row chunk
  const int slot = ln & 31;   // 16B slot within row

  // stage w[0:64][K0:K0+BK] into wlds[b]; LDS linear, source pre-swizzled
  // (slot s of row r holds w cols (s^(r&7))*4 ..+4) so swizzled reads are
  // bank-optimal (each bank exactly 8 accesses per b128).
  #define STAGE(b, K0)                                                    \
    {                                                                     \
      _Pragma("unroll")                                                   \
      for (int i = 0; i < 8; ++i) {                                       \
        const int chunk = wv * 8 + i;            /* wave-uniform */       \
        const int r = 2 * chunk + lrow;          /* expert row   */       \
        const int sg = slot ^ (r & 7);           /* src col-group */      \
        gload16(gw + r * DIM + (K0) + sg * 4, &wlds[b][chunk * 256]);     \
      }                                                                   \
    }

  STAGE(0, 0);

  float acc[TPW][2] = {};
  const unsigned long long xbase =
      (unsigned long long)(const void*)(x + (size_t)tokw * DIM);

  __syncthreads();

  for (int step = 0; step < NSTEP; ++step) {
    const int cur = step & 1;
    if (step + 1 < NSTEP) STAGE(cur ^ 1, (step + 1) * BK);

    const f4* wp = reinterpret_cast<const f4*>(&wlds[cur][0]);
    cf4p xp = reinterpret_cast<cf4p>(xbase + (unsigned long long)step * BK * 4);

    #pragma unroll 2
    for (int c = 0; c < NCHUNK; ++c) {
      const int s0 = 2 * c, s1 = 2 * c + 1;
      const f4 w0 = wp[ln * 32 + (s0 ^ (ln & 7))];
      const f4 w1 = wp[ln * 32 + (s1 ^ (ln & 7))];
      #pragma unroll
      for (int tt = 0; tt < TPW; ++tt) {
        const f4 a0 = xp[tt * (DIM / 4) + s0];   // scalar loads (uniform)
        const f4 a1 = xp[tt * (DIM / 4) + s1];
        float u = acc[tt][0], v = acc[tt][1];
        u = fmaf(a0.x, w0.x, u); u = fmaf(a0.y, w0.y, u);
        u = fmaf(a0.z, w0.z, u); u = fmaf(a0.w, w0.w, u);
        v = fmaf(a1.x, w1.x, v); v = fmaf(a1.y, w1.y, v);
        v = fmaf(a1.z, w1.z, v); v = fmaf(a1.w, w1.w, v);
        acc[tt][0] = u; acc[tt][1] = v;
      }
    }
    __syncthreads();
  }

  // ---- epilogue: per token (wave-local; lane = expert) ----
  const float INVT = 0.36787944117144233f;  // 1/e
  #pragma unroll 1
  for (int tt = 0; tt < TPW; ++tt) {
    const int tok = tokw + tt;
    const float s = (acc[tt][0] + acc[tt][1]) * INVT;

    // bitonic sort ascending across 64 lanes
    float v = s;
    #pragma unroll
    for (int k = 2; k <= 64; k <<= 1) {
      #pragma unroll
      for (int j = k >> 1; j > 0; j >>= 1) {
        const float o = __shfl_xor(v, j, 64);
        const bool up = ((ln & k) == 0);
        const bool lo = ((ln & j) == 0);
        v = (lo == up) ? fminf(v, o) : fmaxf(v, o);
      }
    }
    const float v20 = __shfl(v, 64 - NACT, 64);      // 21st smallest = thr
    const float v19 = __shfl(v, 64 - NACT - 1, 64);  // 20th smallest

    bool sel;
    float sv = s;
    if (v20 - v19 < GAP_EPS) {
      // borderline: recompute this token's 64 scores in f64, re-rank (rare)
      const f4* xr = reinterpret_cast<const f4*>(x + (size_t)tok * DIM);
      const f4* wr = reinterpret_cast<const f4*>(gw + (size_t)ln * DIM);
      double p0=0,p1=0,p2=0,p3=0,p4=0,p5=0,p6=0,p7=0;
      for (int k = 0; k < DIM / 8; ++k) {
        const f4 xa = xr[2*k], xb = xr[2*k+1];
        const f4 wa = wr[2*k], wb = wr[2*k+1];
        p0 = fma((double)xa.x, (double)wa.x, p0);
        p1 = fma((double)xa.y, (double)wa.y, p1);
        p2 = fma((double)xa.z, (double)wa.z, p2);
        p3 = fma((double)xa.w, (double)wa.w, p3);
        p4 = fma((double)xb.x, (double)wb.x, p4);
        p5 = fma((double)xb.y, (double)wb.y, p5);
        p6 = fma((double)xb.z, (double)wb.z, p6);
        p7 = fma((double)xb.w, (double)wb.w, p7);
      }
      const double s64 =
          (((p0+p1)+(p2+p3)) + ((p4+p5)+(p6+p7))) * 0.36787944117144233;
      double dv = s64;
      #pragma unroll
      for (int k = 2; k <= 64; k <<= 1) {
        #pragma unroll
        for (int j = k >> 1; j > 0; j >>= 1) {
          const double o = __shfl_xor(dv, j, 64);
          const bool up = ((ln & k) == 0);
          const bool lo = ((ln & j) == 0);
          dv = (lo == up) ? fmin(dv, o) : fmax(dv, o);
        }
      }
      const double thr64 = __shfl(dv, 64 - NACT, 64);
      sel = (s64 >= thr64);
      sv = (float)s64;
    } else {
      sel = (s >= v20);
    }

    const float mx = wave_max(sv);
    const float ex = __expf(sv - mx);
    const float sum = wave_sum(ex);
    const float p = ex / sum;
    const float ps = wave_sum(sel ? p : 0.0f);
    out[(size_t)tok * NEXP + ln] = sel ? (p / (ps + 1e-8f)) : 0.0f;
  }
}

extern "C" void kernel_launch(void* const* d_in, const int* in_sizes, int n_in,
                              void* d_out, int out_size, void* d_ws, size_t ws_size,
                              hipStream_t stream) {
  const float* x  = (const float*)d_in[0];
  const float* gw = (const float*)d_in[1];
  float* out = (float*)d_out;
  boltzmann_router_kernel<<<dim3(NTOK / BM), dim3(256), 0, stream>>>(x, gw, out);
}

// Round 4
// 308.577 us; speedup vs baseline: 1.4711x; 1.4711x over previous
//
#include <hip/hip_runtime.h>

// BoltzmannRouter: weights = renorm(top44(softmax(x @ gate_w^T / e)))
// x: (4,4096,2048) f32 ; gate_w: (64,2048) f32 ; out: (4,4096,64) f32
//
// HBM-bound design (floor: 132 MB / 6.3 TB/s ~= 21 us):
//   scores via 3-pass bf16 MFMA split (hi=trunc16, lo=bf16rn(x-hi)):
//     x.w ~= xhi.whi + xhi.wlo + xlo.whi   (dropped xlo.wlo ~ 3e-6 sigma)
//   selection safety: if f32 gap between ranks 20/21 < GAP_EPS, recompute
//   that token's 64 dots in f64 and re-rank (R3-proven path, ~1% of tokens).
// Layout (m89/m90-verified): A,B frags row=lane&15, kgroup=lane>>4;
// D: col=lane&15, row=(lane>>4)*4+reg.
// BM=32 tokens/block, 4 waves (2 token-halves x 2 expert-halves), grid 512
// -> 2 blocks/CU. x: global->reg A-frags (no LDS). w: reg-stage+convert->
// LDS dbuf, XOR-swizzled slot^(exp&7) on both write and read.

#define NTOK   16384
#define DIM    2048
#define NEXP   64
#define NACT   44
#define BM     32
#define BK     64
#define NSTEP  (DIM / BK)   // 32
#define GAP_EPS 2e-4f

typedef __attribute__((ext_vector_type(4))) float f4;
typedef __attribute__((ext_vector_type(8))) short bf8;
typedef __attribute__((ext_vector_type(4))) float f32x4;

union BF8U { unsigned u[4]; bf8 v; };

__device__ __forceinline__ unsigned bf16rn(float f) {
  unsigned u = __float_as_uint(f);
  return (u + 0x7fffu + ((u >> 16) & 1u)) >> 16;
}

// split 8 f32 -> hi (truncated top-16) + lo (bf16rn of exact residual)
__device__ __forceinline__ void split8t(f4 a, f4 b, bf8& hi, bf8& lo) {
  float fa[8] = {a.x, a.y, a.z, a.w, b.x, b.y, b.z, b.w};
  BF8U h, l;
  #pragma unroll
  for (int j = 0; j < 4; ++j) {
    const float f0 = fa[2 * j], f1 = fa[2 * j + 1];
    const unsigned u0 = __float_as_uint(f0), u1 = __float_as_uint(f1);
    const unsigned h0 = u0 & 0xffff0000u, h1 = u1 & 0xffff0000u;
    h.u[j] = (u0 >> 16) | h1;
    const float l0 = f0 - __uint_as_float(h0);   // exact
    const float l1 = f1 - __uint_as_float(h1);   // exact
    l.u[j] = bf16rn(l0) | (bf16rn(l1) << 16);
  }
  hi = h.v; lo = l.v;
}

__device__ __forceinline__ float wave_max(float v) {
  #pragma unroll
  for (int j = 32; j > 0; j >>= 1) v = fmaxf(v, __shfl_xor(v, j, 64));
  return v;
}
__device__ __forceinline__ float wave_sum(float v) {
  #pragma unroll
  for (int j = 32; j > 0; j >>= 1) v += __shfl_xor(v, j, 64);
  return v;
}

__global__ __launch_bounds__(256, 2) void boltzmann_router_kernel(
    const float* __restrict__ x, const float* __restrict__ gw,
    float* __restrict__ out) {
  __shared__ unsigned short whi[2][NEXP * BK];  // 16 KB
  __shared__ unsigned short wlo[2][NEXP * BK];  // 16 KB

  const int t    = threadIdx.x;
  const int ln   = t & 63;
  const int wv   = t >> 6;
  const int tw   = wv >> 1;   // token half 0/1
  const int nh   = wv & 1;    // expert half 0/1
  const int tok0 = blockIdx.x * BM;

  // w staging: thread t covers exp row t>>2, 16 floats at chunk (t&3)*16
  const int wexp = t >> 2;
  const int wko  = (t & 3) * 16;
  const int ws0  = (t & 3) * 2;        // logical 8-elem k-slot
  const int we7  = wexp & 7;

  // x (A-frag) source: lane owns row tw*16+(ln&15), kgroup ln>>4
  const int xrow = tok0 + tw * 16 + (ln & 15);
  const int xk   = (ln >> 4) * 8;

  f4 xbuf[4], wbuf[4];
  bf8 ahi[2], alo[2];

  auto issue_loads = [&](int step) {
    const float* xp = x + (size_t)xrow * DIM + step * BK + xk;
    xbuf[0] = *(const f4*)(xp);
    xbuf[1] = *(const f4*)(xp + 4);
    xbuf[2] = *(const f4*)(xp + 32);
    xbuf[3] = *(const f4*)(xp + 36);
    const float* wp = gw + (size_t)wexp * DIM + step * BK + wko;
    wbuf[0] = *(const f4*)(wp);
    wbuf[1] = *(const f4*)(wp + 4);
    wbuf[2] = *(const f4*)(wp + 8);
    wbuf[3] = *(const f4*)(wp + 12);
  };
  auto convert_store = [&](int buf) {
    split8t(xbuf[0], xbuf[1], ahi[0], alo[0]);   // khalf 0
    split8t(xbuf[2], xbuf[3], ahi[1], alo[1]);   // khalf 1
    bf8 h0, l0, h1, l1;
    split8t(wbuf[0], wbuf[1], h0, l0);           // logical slot ws0
    split8t(wbuf[2], wbuf[3], h1, l1);           // logical slot ws0+1
    const int p0 = ((ws0 ^ we7) * 8), p1 = (((ws0 + 1) ^ we7) * 8);
    *reinterpret_cast<bf8*>(&whi[buf][wexp * 64 + p0]) = h0;
    *reinterpret_cast<bf8*>(&whi[buf][wexp * 64 + p1]) = h1;
    *reinterpret_cast<bf8*>(&wlo[buf][wexp * 64 + p0]) = l0;
    *reinterpret_cast<bf8*>(&wlo[buf][wexp * 64 + p1]) = l1;
  };

  issue_loads(0);
  convert_store(0);
  __syncthreads();

  f32x4 acc[2] = {};
  for (int step = 0; step < NSTEP; ++step) {
    const int cur = step & 1;
    if (step + 1 < NSTEP) issue_loads(step + 1);
    #pragma unroll
    for (int h = 0; h < 2; ++h) {
      #pragma unroll
      for (int nf = 0; nf < 2; ++nf) {
        const int ee  = nh * 32 + nf * 16 + (ln & 15);
        const int ps  = ((h * 4 + (ln >> 4)) ^ (ln & 7)) * 8;
        const int idx = ee * 64 + ps;
        const bf8 bh = *reinterpret_cast<const bf8*>(&whi[cur][idx]);
        const bf8 bl = *reinterpret_cast<const bf8*>(&wlo[cur][idx]);
        acc[nf] = __builtin_amdgcn_mfma_f32_16x16x32_bf16(ahi[h], bh, acc[nf], 0, 0, 0);
        acc[nf] = __builtin_amdgcn_mfma_f32_16x16x32_bf16(alo[h], bh, acc[nf], 0, 0, 0);
        acc[nf] = __builtin_amdgcn_mfma_f32_16x16x32_bf16(ahi[h], bl, acc[nf], 0, 0, 0);
      }
    }
    if (step + 1 < NSTEP) convert_store(cur ^ 1);
    __syncthreads();
  }

  // ---- scores to LDS (overlay on whi; 32*65*4 = 8.3 KB < 16 KB) ----
  float* sc = reinterpret_cast<float*>(&whi[0][0]);
  const float INVT = 0.36787944117144233f;  // 1/e
  #pragma unroll
  for (int nf = 0; nf < 2; ++nf) {
    #pragma unroll
    for (int r = 0; r < 4; ++r) {
      const int tokr = tw * 16 + (ln >> 4) * 4 + r;       // D row
      const int expc = nh * 32 + nf * 16 + (ln & 15);     // D col
      sc[tokr * 65 + expc] = acc[nf][r] * INVT;
    }
  }
  __syncthreads();

  // ---- per-token: top-44 threshold + gap fixup + softmax + renorm ----
  #pragma unroll 1
  for (int it = 0; it < 8; ++it) {
    const int m   = wv * 8 + it;
    const int tok = tok0 + m;
    const float s = sc[m * 65 + ln];

    float v = s;  // bitonic sort ascending across 64 lanes
    #pragma unroll
    for (int k = 2; k <= 64; k <<= 1) {
      #pragma unroll
      for (int j = k >> 1; j > 0; j >>= 1) {
        const float o  = __shfl_xor(v, j, 64);
        const bool up  = ((ln & k) == 0);
        const bool lo_ = ((ln & j) == 0);
        v = (lo_ == up) ? fminf(v, o) : fmaxf(v, o);
      }
    }
    const float v20 = __shfl(v, 64 - NACT, 64);      // 21st smallest = thr
    const float v19 = __shfl(v, 64 - NACT - 1, 64);  // 20th smallest

    bool sel;
    float sv = s;
    if (v20 - v19 < GAP_EPS) {  // borderline: exact f64 re-rank (rare)
      const f4* xr = reinterpret_cast<const f4*>(x + (size_t)tok * DIM);
      const f4* wr = reinterpret_cast<const f4*>(gw + (size_t)ln * DIM);
      double p0=0,p1=0,p2=0,p3=0,p4=0,p5=0,p6=0,p7=0;
      for (int k = 0; k < DIM / 8; ++k) {
        const f4 xa = xr[2*k], xb = xr[2*k+1];
        const f4 wa = wr[2*k], wb = wr[2*k+1];
        p0 = fma((double)xa.x, (double)wa.x, p0);
        p1 = fma((double)xa.y, (double)wa.y, p1);
        p2 = fma((double)xa.z, (double)wa.z, p2);
        p3 = fma((double)xa.w, (double)wa.w, p3);
        p4 = fma((double)xb.x, (double)wb.x, p4);
        p5 = fma((double)xb.y, (double)wb.y, p5);
        p6 = fma((double)xb.z, (double)wb.z, p6);
        p7 = fma((double)xb.w, (double)wb.w, p7);
      }
      const double s64 =
          (((p0+p1)+(p2+p3)) + ((p4+p5)+(p6+p7))) * 0.36787944117144233;
      double dv = s64;
      #pragma unroll
      for (int k = 2; k <= 64; k <<= 1) {
        #pragma unroll
        for (int j = k >> 1; j > 0; j >>= 1) {
          const double o = __shfl_xor(dv, j, 64);
          const bool up  = ((ln & k) == 0);
          const bool lo_ = ((ln & j) == 0);
          dv = (lo_ == up) ? fmin(dv, o) : fmax(dv, o);
        }
      }
      const double thr64 = __shfl(dv, 64 - NACT, 64);
      sel = (s64 >= thr64);
      sv = (float)s64;
    } else {
      sel = (s >= v20);
    }

    const float mx  = wave_max(sv);
    const float ex  = __expf(sv - mx);
    const float sum = wave_sum(ex);
    const float p   = ex / sum;
    const float ps  = wave_sum(sel ? p : 0.0f);
    out[(size_t)tok * NEXP + ln] = sel ? (p / (ps + 1e-8f)) : 0.0f;
  }
}

extern "C" void kernel_launch(void* const* d_in, const int* in_sizes, int n_in,
                              void* d_out, int out_size, void* d_ws, size_t ws_size,
                              hipStream_t stream) {
  const float* x  = (const float*)d_in[0];
  const float* gw = (const float*)d_in[1];
  float* out = (float*)d_out;
  boltzmann_router_kernel<<<dim3(NTOK / BM), dim3(256), 0, stream>>>(x, gw, out);
}

// Round 5
// 281.069 us; speedup vs baseline: 1.6151x; 1.0979x over previous
//
#include <hip/hip_runtime.h>

// BoltzmannRouter: weights = renorm(top44(softmax(x @ gate_w^T / e)))
// x: (4,4096,2048) f32 ; gate_w: (64,2048) f32 ; out: (4,4096,64) f32
//
// Two kernels:
//  1) split_w: gate_w f32 -> bf16 hi/lo images in d_ws, laid out exactly as
//     the per-step LDS tiles (XOR swizzle ls=gs^(e&7) pre-applied).
//  2) router: 3-deep global_load_lds pipeline (counted vmcnt, raw s_barrier,
//     never drain to 0 mid-loop) staging x raw f32 + whi/wlo bf16 tiles;
//     3-pass bf16 MFMA split (xhi.whi + xhi.wlo + xlo.whi); proven epilogue
//     (bitonic top-44 + f64 fixup when rank-20/21 gap < GAP_EPS).
// MFMA layout conventions HW-verified by R4 (passed, absmax 4.9e-4).

#define NTOK  16384
#define DIM   2048
#define NEXP  64
#define NACT  44
#define BM    64
#define BK    64
#define NSTEP (DIM / BK)   // 32
#define GAP_EPS 2e-4f

typedef __attribute__((ext_vector_type(4))) float f4;
typedef __attribute__((ext_vector_type(8))) short bf8;
typedef __attribute__((ext_vector_type(4))) float f32x4;

union BF8U { unsigned u[4]; bf8 v; };

__device__ __forceinline__ unsigned bf16rn(float f) {
  unsigned u = __float_as_uint(f);
  return (u + 0x7fffu + ((u >> 16) & 1u)) >> 16;
}

// split 8 f32 -> hi (truncated top-16 bits) + lo (bf16rn of exact residual)
__device__ __forceinline__ void split8t(f4 a, f4 b, bf8& hi, bf8& lo) {
  float fa[8] = {a.x, a.y, a.z, a.w, b.x, b.y, b.z, b.w};
  BF8U h, l;
  #pragma unroll
  for (int j = 0; j < 4; ++j) {
    const float f0 = fa[2 * j], f1 = fa[2 * j + 1];
    const unsigned u0 = __float_as_uint(f0), u1 = __float_as_uint(f1);
    const unsigned h0 = u0 & 0xffff0000u, h1 = u1 & 0xffff0000u;
    h.u[j] = (u0 >> 16) | h1;
    const float l0 = f0 - __uint_as_float(h0);   // exact
    const float l1 = f1 - __uint_as_float(h1);   // exact
    l.u[j] = bf16rn(l0) | (bf16rn(l1) << 16);
  }
  hi = h.v; lo = l.v;
}

__device__ __forceinline__ float wave_max(float v) {
  #pragma unroll
  for (int j = 32; j > 0; j >>= 1) v = fmaxf(v, __shfl_xor(v, j, 64));
  return v;
}
__device__ __forceinline__ float wave_sum(float v) {
  #pragma unroll
  for (int j = 32; j > 0; j >>= 1) v += __shfl_xor(v, j, 64);
  return v;
}

// ---- kernel 1: pre-split w into per-step LDS-image layout -----------------
__global__ __launch_bounds__(256) void split_w_kernel(
    const float* __restrict__ gw, unsigned short* __restrict__ whi_g,
    unsigned short* __restrict__ wlo_g) {
  const int i  = blockIdx.x * 256 + threadIdx.x;   // 0..16383 (16B slots)
  const int s  = i >> 9;          // step
  const int r  = (i >> 3) & 63;   // expert row
  const int ls = i & 7;           // LDS slot within row
  const int gs = ls ^ (r & 7);    // swizzle pre-applied
  const float* src = gw + (size_t)r * DIM + s * BK + gs * 8;
  const f4 a = *reinterpret_cast<const f4*>(src);
  const f4 b = *reinterpret_cast<const f4*>(src + 4);
  bf8 hi, lo;
  split8t(a, b, hi, lo);
  *reinterpret_cast<bf8*>(whi_g + (size_t)i * 8) = hi;
  *reinterpret_cast<bf8*>(wlo_g + (size_t)i * 8) = lo;
}

// ---- kernel 2: fused router ------------------------------------------------
__global__ __launch_bounds__(512, 1) void boltzmann_router_kernel(
    const float* __restrict__ x, const float* __restrict__ gw,
    const unsigned short* __restrict__ whi_g,
    const unsigned short* __restrict__ wlo_g, float* __restrict__ out) {
  __shared__ alignas(16) float          xlds[3][BM * BK];     // 48 KB
  __shared__ alignas(16) unsigned short whilds[3][NEXP * BK]; // 24 KB
  __shared__ alignas(16) unsigned short wlolds[3][NEXP * BK]; // 24 KB

  const int t    = threadIdx.x;
  const int ln   = t & 63;
  const int wv   = t >> 6;     // 0..7
  const int tq   = wv >> 1;    // token quarter
  const int nh   = wv & 1;     // expert half
  const int tok0 = blockIdx.x * BM;

  // staging roles: waves 0-3 stage x (16 x 1KB), 4-5 whi, 6-7 wlo.
  // Every wave issues exactly 4 gload_lds per tile -> vmcnt counting works.
  size_t gsrc[4];
  if (wv < 4) {
    #pragma unroll
    for (int i = 0; i < 4; ++i) {
      const int c  = wv * 4 + i;
      const int r  = 4 * c + (ln >> 4);
      const int gs = (ln & 15) ^ (r & 15);     // pre-swizzled source
      gsrc[i] = (size_t)(tok0 + r) * DIM + gs * 4;
    }
  } else {
    const int base = ((wv - 4) & 1) * 4;       // wv 4,6 -> 0 ; wv 5,7 -> 4
    #pragma unroll
    for (int i = 0; i < 4; ++i) {
      const int c2 = base + i;
      gsrc[i] = (size_t)c2 * 512 + ln * 8;
    }
  }

  auto STAGE = [&](int buf, int step) {
    if (wv < 4) {
      #pragma unroll
      for (int i = 0; i < 4; ++i) {
        const int c = wv * 4 + i;
        __builtin_amdgcn_global_load_lds(
            (const __attribute__((address_space(1))) void*)(x + gsrc[i] + (size_t)step * BK),
            (__attribute__((address_space(3))) void*)&xlds[buf][c * 256], 16, 0, 0);
      }
    } else if (wv < 6) {
      #pragma unroll
      for (int i = 0; i < 4; ++i) {
        const int c2 = (wv - 4) * 4 + i;
        __builtin_amdgcn_global_load_lds(
            (const __attribute__((address_space(1))) void*)(whi_g + gsrc[i] + (size_t)step * 4096),
            (__attribute__((address_space(3))) void*)&whilds[buf][c2 * 512], 16, 0, 0);
      }
    } else {
      #pragma unroll
      for (int i = 0; i < 4; ++i) {
        const int c2 = (wv - 6) * 4 + i;
        __builtin_amdgcn_global_load_lds(
            (const __attribute__((address_space(1))) void*)(wlo_g + gsrc[i] + (size_t)step * 4096),
            (__attribute__((address_space(3))) void*)&wlolds[buf][c2 * 512], 16, 0, 0);
      }
    }
  };

  STAGE(0, 0);
  STAGE(1, 1);
  STAGE(2, 2);

  const int arow = tq * 16 + (ln & 15);   // A-frag row (token within tile)
  f32x4 acc[2] = {};

  int cur = 0;
  for (int step = 0; step < NSTEP; ++step) {
    // counted wait: oldest tile's loads done, 2 tiles stay in flight
    if (step < NSTEP - 2)       asm volatile("s_waitcnt vmcnt(8)" ::: "memory");
    else if (step == NSTEP - 2) asm volatile("s_waitcnt vmcnt(4)" ::: "memory");
    else                        asm volatile("s_waitcnt vmcnt(0)" ::: "memory");
    __builtin_amdgcn_s_barrier();

    // A frags: raw f32 from LDS, split in-register (once per element)
    bf8 ahi[2], alo[2];
    #pragma unroll
    for (int ks = 0; ks < 2; ++ks) {
      const int gs0 = ks * 8 + (ln >> 4) * 2;
      const int ls0 = gs0 ^ (arow & 15);
      const int ls1 = (gs0 + 1) ^ (arow & 15);
      const f4 a0 = *reinterpret_cast<const f4*>(&xlds[cur][arow * 64 + ls0 * 4]);
      const f4 a1 = *reinterpret_cast<const f4*>(&xlds[cur][arow * 64 + ls1 * 4]);
      split8t(a0, a1, ahi[ks], alo[ks]);
    }
    // B frags: direct bf16 ds_read_b128 (1 read = 1 frag), 3-pass MFMA
    #pragma unroll
    for (int nf = 0; nf < 2; ++nf) {
      const int e = nh * 32 + nf * 16 + (ln & 15);
      #pragma unroll
      for (int ks = 0; ks < 2; ++ks) {
        const int gs = ks * 4 + (ln >> 4);
        const int ls = gs ^ (e & 7);
        const bf8 bh = *reinterpret_cast<const bf8*>(&whilds[cur][e * 64 + ls * 8]);
        const bf8 bl = *reinterpret_cast<const bf8*>(&wlolds[cur][e * 64 + ls * 8]);
        acc[nf] = __builtin_amdgcn_mfma_f32_16x16x32_bf16(ahi[ks], bh, acc[nf], 0, 0, 0);
        acc[nf] = __builtin_amdgcn_mfma_f32_16x16x32_bf16(alo[ks], bh, acc[nf], 0, 0, 0);
        acc[nf] = __builtin_amdgcn_mfma_f32_16x16x32_bf16(ahi[ks], bl, acc[nf], 0, 0, 0);
      }
    }
    __builtin_amdgcn_s_barrier();          // all waves done reading buf[cur]
    if (step + 3 < NSTEP) STAGE(cur, step + 3);
    cur = (cur == 2) ? 0 : cur + 1;
  }

  // ---- scores to LDS (overlay on xlds; 64*65*4 = 16.6 KB) ----
  float* sc = reinterpret_cast<float*>(&xlds[0][0]);
  const float INVT = 0.36787944117144233f;  // 1/e
  #pragma unroll
  for (int nf = 0; nf < 2; ++nf) {
    #pragma unroll
    for (int r = 0; r < 4; ++r) {
      const int tokr = tq * 16 + (ln >> 4) * 4 + r;    // D row
      const int expc = nh * 32 + nf * 16 + (ln & 15);  // D col
      sc[tokr * 65 + expc] = acc[nf][r] * INVT;
    }
  }
  __syncthreads();

  // ---- per-token: top-44 threshold + gap fixup + softmax + renorm ----
  #pragma unroll 1
  for (int it = 0; it < 8; ++it) {
    const int m   = wv * 8 + it;
    const int tok = tok0 + m;
    const float s = sc[m * 65 + ln];

    float v = s;  // bitonic sort ascending across 64 lanes
    #pragma unroll
    for (int k = 2; k <= 64; k <<= 1) {
      #pragma unroll
      for (int j = k >> 1; j > 0; j >>= 1) {
        const float o  = __shfl_xor(v, j, 64);
        const bool up  = ((ln & k) == 0);
        const bool lo_ = ((ln & j) == 0);
        v = (lo_ == up) ? fminf(v, o) : fmaxf(v, o);
      }
    }
    const float v20 = __shfl(v, 64 - NACT, 64);      // 21st smallest = thr
    const float v19 = __shfl(v, 64 - NACT - 1, 64);  // 20th smallest

    bool sel;
    float sv = s;
    if (v20 - v19 < GAP_EPS) {  // borderline: exact f64 re-rank (rare)
      const f4* xr = reinterpret_cast<const f4*>(x + (size_t)tok * DIM);
      const f4* wr = reinterpret_cast<const f4*>(gw + (size_t)ln * DIM);
      double p0=0,p1=0,p2=0,p3=0,p4=0,p5=0,p6=0,p7=0;
      for (int k = 0; k < DIM / 8; ++k) {
        const f4 xa = xr[2*k], xb = xr[2*k+1];
        const f4 wa = wr[2*k], wb = wr[2*k+1];
        p0 = fma((double)xa.x, (double)wa.x, p0);
        p1 = fma((double)xa.y, (double)wa.y, p1);
        p2 = fma((double)xa.z, (double)wa.z, p2);
        p3 = fma((double)xa.w, (double)wa.w, p3);
        p4 = fma((double)xb.x, (double)wb.x, p4);
        p5 = fma((double)xb.y, (double)wb.y, p5);
        p6 = fma((double)xb.z, (double)wb.z, p6);
        p7 = fma((double)xb.w, (double)wb.w, p7);
      }
      const double s64 =
          (((p0+p1)+(p2+p3)) + ((p4+p5)+(p6+p7))) * 0.36787944117144233;
      double dv = s64;
      #pragma unroll
      for (int k = 2; k <= 64; k <<= 1) {
        #pragma unroll
        for (int j = k >> 1; j > 0; j >>= 1) {
          const double o = __shfl_xor(dv, j, 64);
          const bool up  = ((ln & k) == 0);
          const bool lo_ = ((ln & j) == 0);
          dv = (lo_ == up) ? fmin(dv, o) : fmax(dv, o);
        }
      }
      const double thr64 = __shfl(dv, 64 - NACT, 64);
      sel = (s64 >= thr64);
      sv = (float)s64;
    } else {
      sel = (s >= v20);
    }

    const float mx  = wave_max(sv);
    const float ex  = __expf(sv - mx);
    const float sum = wave_sum(ex);
    const float p   = ex / sum;
    const float ps  = wave_sum(sel ? p : 0.0f);
    out[(size_t)tok * NEXP + ln] = sel ? (p / (ps + 1e-8f)) : 0.0f;
  }
}

extern "C" void kernel_launch(void* const* d_in, const int* in_sizes, int n_in,
                              void* d_out, int out_size, void* d_ws, size_t ws_size,
                              hipStream_t stream) {
  const float* x  = (const float*)d_in[0];
  const float* gw = (const float*)d_in[1];
  float* out = (float*)d_out;
  unsigned short* whi_g = (unsigned short*)d_ws;        // 131072 bf16 (256 KB)
  unsigned short* wlo_g = whi_g + (size_t)NEXP * DIM;   // 131072 bf16 (256 KB)
  split_w_kernel<<<dim3(64), dim3(256), 0, stream>>>(gw, whi_g, wlo_g);
  boltzmann_router_kernel<<<dim3(NTOK / BM), dim3(512), 0, stream>>>(
      x, gw, whi_g, wlo_g, out);
}